// Round 14
// baseline (566.346 us; speedup 1.0000x reference)
//
#include <hip/hip_runtime.h>
#include <hip/hip_fp8.h>

#define N_NODES 100000
#define N_EDGES 1600000
#define ETOT (N_EDGES + N_NODES)
#define IN_F 128
#define HID 32
#define HEADS 8
#define CDIM (HEADS * HID) /* 256 */
#define GRAPHS 64
#define CLASSES 10
#define NEG_SLOPE 0.2f

#define BSHIFT 7                       /* 128 nodes per bucket */
#define NBUCK ((N_NODES + 127) >> BSHIFT) /* 782 */
#define BCAP 2600                      /* mean 2176, sigma ~45 -> 9+ sigma margin */
#define BIN_BLOCKS 160

static inline int ceil_div(int a, int b) { return (a + b - 1) / b; }

typedef __attribute__((ext_vector_type(8))) short bf16x8;
typedef __attribute__((ext_vector_type(4))) float f32x4;
typedef __attribute__((ext_vector_type(2))) float f32x2;

// bf16 <-> f32 helpers (round-to-nearest-even; inputs are finite)
__device__ inline unsigned short f2bf(float f) {
    unsigned u = __float_as_uint(f);
    unsigned r = (u + 0x7FFFu + ((u >> 16) & 1u)) >> 16;
    return (unsigned short)r;
}
__device__ inline float bf2f(unsigned short v) {
    return __uint_as_float(((unsigned)v) << 16);
}
// fp8 e4m3 (OCP) encode — HIP class (epilogues only, not hot loops)
__device__ inline unsigned char f2fp8(float f) {
    __hip_fp8_e4m3 v(f);
    return (unsigned char)v.__x;
}
// fp8 decode: HW packed cvt (byte-select is a compile-time template constant)
#if __has_builtin(__builtin_amdgcn_cvt_pk_f32_fp8)
template<bool HI>
__device__ inline f32x2 fp8pair(unsigned w) {
    return __builtin_amdgcn_cvt_pk_f32_fp8((int)w, HI);
}
#else
template<bool HI>
__device__ inline f32x2 fp8pair(unsigned w) {
    unsigned b0 = HI ? ((w >> 16) & 0xff) : (w & 0xff);
    unsigned b1 = HI ? (w >> 24) : ((w >> 8) & 0xff);
    __hip_fp8_e4m3 v0, v1;
    v0.__x = (__hip_fp8_storage_t)b0;
    v1.__x = (__hip_fp8_storage_t)b1;
    f32x2 r; r[0] = (float)v0; r[1] = (float)v1;
    return r;
}
#endif
__device__ inline float fp8one(unsigned char b) {
#if __has_builtin(__builtin_amdgcn_cvt_f32_fp8)
    return __builtin_amdgcn_cvt_f32_fp8((int)b, 0);
#else
    __hip_fp8_e4m3 v;
    v.__x = (__hip_fp8_storage_t)b;
    return (float)v;
#endif
}
// 8 fp8 (uint2) -> 8 bf16, ascending element order
__device__ inline bf16x8 fp8x8_to_bf16(uint2 w) {
    f32x2 p0 = fp8pair<false>(w.x), p1 = fp8pair<true>(w.x);
    f32x2 p2 = fp8pair<false>(w.y), p3 = fp8pair<true>(w.y);
    bf16x8 r;
    r[0] = (short)f2bf(p0[0]); r[1] = (short)f2bf(p0[1]);
    r[2] = (short)f2bf(p1[0]); r[3] = (short)f2bf(p1[1]);
    r[4] = (short)f2bf(p2[0]); r[5] = (short)f2bf(p2[1]);
    r[6] = (short)f2bf(p3[0]); r[7] = (short)f2bf(p3[1]);
    return r;
}

// ---------------- CSR build: block-counted binning (dense line writes) ----------------

__global__ __launch_bounds__(256) void bin_kernel(const int* __restrict__ ei,
                                                  int* __restrict__ bcursor,
                                                  unsigned* __restrict__ staged) {
    __shared__ int lhist[NBUCK];
    __shared__ int lbase[NBUCK];
    const int t = threadIdx.x;
    const int chunk = (ETOT + gridDim.x - 1) / gridDim.x;
    const int e0 = blockIdx.x * chunk;
    const int e1 = min(e0 + chunk, ETOT);
    for (int b = t; b < NBUCK; b += 256) lhist[b] = 0;
    __syncthreads();
    for (int e = e0 + t; e < e1; e += 256) {
        int d = (e < N_EDGES) ? ei[N_EDGES + e] : (e - N_EDGES);
        atomicAdd(&lhist[d >> BSHIFT], 1);
    }
    __syncthreads();
    for (int b = t; b < NBUCK; b += 256) {
        int c = lhist[b];
        lbase[b] = c ? atomicAdd(&bcursor[b * 16], c) : 0;
        lhist[b] = 0;
    }
    __syncthreads();
    for (int e = e0 + t; e < e1; e += 256) {
        int s, d;
        if (e < N_EDGES) { s = ei[e]; d = ei[N_EDGES + e]; }
        else { s = e - N_EDGES; d = s; }
        int b = d >> BSHIFT;
        int off = atomicAdd(&lhist[b], 1);
        staged[(size_t)b * BCAP + lbase[b] + off] =
            ((unsigned)s << BSHIFT) | (unsigned)(d & 127);
    }
}

__global__ __launch_bounds__(1024) void bscan_kernel(const int* __restrict__ bcursor,
                                                     int* __restrict__ bbase,
                                                     int* __restrict__ rowptr) {
    __shared__ int tmp[1024];
    int i = threadIdx.x;
    int v = (i < NBUCK) ? bcursor[i * 16] : 0;
    tmp[i] = v;
    __syncthreads();
    for (int off = 1; off < 1024; off <<= 1) {
        int t = (i >= off) ? tmp[i - off] : 0;
        __syncthreads();
        tmp[i] += t;
        __syncthreads();
    }
    if (i < NBUCK) bbase[i] = tmp[i] - v; // exclusive
    if (i == NBUCK - 1) { bbase[NBUCK] = tmp[i]; rowptr[N_NODES] = tmp[i]; }
}

// srcoff stores s*CDIM (byte offset into the fp8 payload row) — 32-bit.
__global__ __launch_bounds__(256) void build_kernel(
    const unsigned* __restrict__ staged, const int* __restrict__ bcursor,
    const int* __restrict__ bbase, int* __restrict__ rowptr, unsigned* __restrict__ srcoff) {
    int b = blockIdx.x;
    int cnt = bcursor[b * 16];
    int base = bbase[b];
    __shared__ int lcnt[128];
    __shared__ int lscan[128];
    int t = threadIdx.x;
    if (t < 128) lcnt[t] = 0;
    __syncthreads();
    const unsigned* st = staged + (size_t)b * BCAP;
    for (int i = t; i < cnt; i += 256) atomicAdd(&lcnt[st[i] & 127], 1);
    __syncthreads();
    if (t < 128) lscan[t] = lcnt[t];
    __syncthreads();
    for (int off = 1; off < 128; off <<= 1) {
        int v = 0;
        if (t < 128 && t >= off) v = lscan[t - off];
        __syncthreads();
        if (t < 128) lscan[t] += v;
        __syncthreads();
    }
    int node0 = b << BSHIFT;
    if (t < 128 && node0 + t < N_NODES)
        rowptr[node0 + t] = base + (t == 0 ? 0 : lscan[t - 1]);
    __syncthreads();
    if (t < 128) lcnt[t] = (t == 0 ? 0 : lscan[t - 1]);
    __syncthreads();
    for (int i = t; i < cnt; i += 256) {
        unsigned v = st[i];
        int pos = base + atomicAdd(&lcnt[v & 127], 1);
        srcoff[pos] = (v >> BSHIFT) << 8;   // s * CDIM
    }
}

// ---------------- casts ----------------

// Wt[n][k] = bf16(W[k][n]);  W is [K,N]
__global__ void trcast_kernel(const float* __restrict__ W,
                              unsigned short* __restrict__ Wt, int K, int N) {
    int i = blockIdx.x * blockDim.x + threadIdx.x;
    if (i >= N * K) return;
    int n = i / K, k = i % K;
    Wt[i] = f2bf(W[(size_t)k * N + n]);
}

// ---------------- Block MFMA GEMM (layers 1/2): C[M,256] fp8 = A[M,K] @ Bt[256,K] ----------------
// AMODE: 0 = f32 A (casts to bf16 in staging), 2 = fp8 A (HW-decodes to bf16 in staging).

template<int K, int AMODE>
__global__ __launch_bounds__(512) void gemm_block_kernel(
    const void* __restrict__ Aptr, const unsigned short* __restrict__ Bt,
    unsigned char* __restrict__ C,
    const float* __restrict__ a_src, const float* __restrict__ a_dst,
    float* __restrict__ ALS, float* __restrict__ ALD) {
    constexpr int LDK = K + 8;
    __shared__ unsigned short Alds[64 * LDK];
    const int t = threadIdx.x;
    const int brow = blockIdx.x * 64;

    if (AMODE == 0) {
        const float* A = (const float*)Aptr;
        constexpr int CG = K / 4;
#pragma unroll
        for (int i = 0; i < 64 * CG / 512; ++i) {
            int slot = t + i * 512;
            int row = slot / CG, cg = slot % CG;
            int grow = brow + row;
            float4 v = make_float4(0.f, 0.f, 0.f, 0.f);
            if (grow < N_NODES) v = *(const float4*)(A + (size_t)grow * K + cg * 4);
            ushort4 o;
            o.x = f2bf(v.x); o.y = f2bf(v.y); o.z = f2bf(v.z); o.w = f2bf(v.w);
            *(ushort4*)(Alds + row * LDK + cg * 4) = o;
        }
    } else {
        const unsigned char* A = (const unsigned char*)Aptr;
        constexpr int CG = K / 8;           // 8 fp8 per slot
#pragma unroll
        for (int i = 0; i < 64 * CG / 512; ++i) {
            int slot = t + i * 512;
            int row = slot / CG, cg = slot % CG;
            int grow = brow + row;
            uint2 v = make_uint2(0u, 0u);
            if (grow < N_NODES) v = *(const uint2*)(A + (size_t)grow * K + cg * 8);
            *(bf16x8*)(Alds + row * LDK + cg * 8) = fp8x8_to_bf16(v);
        }
    }
    __syncthreads();

    const int wv = t >> 6;
    const int lane = t & 63;
    const int rhalf = wv & 1;
    const int cpair = wv >> 1;
    const int r = lane & 15;
    const int ko0 = (lane >> 4) * 8;
    const unsigned short* Ar0 = Alds + (rhalf * 32 + r) * LDK + ko0;
    const unsigned short* Ar1 = Alds + (rhalf * 32 + 16 + r) * LDK + ko0;
    const unsigned short* Bq = Bt + (size_t)(cpair * 64 + r) * K + ko0;
    f32x4 acc[2][4];
#pragma unroll
    for (int a = 0; a < 2; ++a)
#pragma unroll
        for (int b = 0; b < 4; ++b) acc[a][b] = {0.f, 0.f, 0.f, 0.f};
#pragma unroll
    for (int k0 = 0; k0 < K; k0 += 32) {
        bf16x8 a0 = *(const bf16x8*)(Ar0 + k0);
        bf16x8 a1 = *(const bf16x8*)(Ar1 + k0);
        bf16x8 b0 = *(const bf16x8*)(Bq + k0);
        bf16x8 b1 = *(const bf16x8*)(Bq + (size_t)16 * K + k0);
        bf16x8 b2 = *(const bf16x8*)(Bq + (size_t)32 * K + k0);
        bf16x8 b3 = *(const bf16x8*)(Bq + (size_t)48 * K + k0);
        acc[0][0] = __builtin_amdgcn_mfma_f32_16x16x32_bf16(a0, b0, acc[0][0], 0, 0, 0);
        acc[0][1] = __builtin_amdgcn_mfma_f32_16x16x32_bf16(a0, b1, acc[0][1], 0, 0, 0);
        acc[0][2] = __builtin_amdgcn_mfma_f32_16x16x32_bf16(a1, b0, acc[0][2], 0, 0, 0);
        acc[0][3] = __builtin_amdgcn_mfma_f32_16x16x32_bf16(a1, b1, acc[0][3], 0, 0, 0);
        acc[1][0] = __builtin_amdgcn_mfma_f32_16x16x32_bf16(a0, b2, acc[1][0], 0, 0, 0);
        acc[1][1] = __builtin_amdgcn_mfma_f32_16x16x32_bf16(a0, b3, acc[1][1], 0, 0, 0);
        acc[1][2] = __builtin_amdgcn_mfma_f32_16x16x32_bf16(a1, b2, acc[1][2], 0, 0, 0);
        acc[1][3] = __builtin_amdgcn_mfma_f32_16x16x32_bf16(a1, b3, acc[1][3], 0, 0, 0);
    }

    const int dcol = lane & 15;
    const int drow = (lane >> 4) * 4;
#pragma unroll
    for (int ti = 0; ti < 2; ++ti) {
        int tn = cpair * 2 + ti;
        float asv0 = a_src[tn * 32 + dcol];
        float asv1 = a_src[tn * 32 + 16 + dcol];
        float adv0 = a_dst[tn * 32 + dcol];
        float adv1 = a_dst[tn * 32 + 16 + dcol];
#pragma unroll
        for (int rg = 0; rg < 4; ++rg) {
            int row0 = brow + rhalf * 32 + drow + rg;
            int row1 = row0 + 16;
            if (row0 < N_NODES) {
                C[(size_t)row0 * CDIM + tn * 32 + dcol]      = f2fp8(acc[ti][0][rg]);
                C[(size_t)row0 * CDIM + tn * 32 + 16 + dcol] = f2fp8(acc[ti][1][rg]);
            }
            if (row1 < N_NODES) {
                C[(size_t)row1 * CDIM + tn * 32 + dcol]      = f2fp8(acc[ti][2][rg]);
                C[(size_t)row1 * CDIM + tn * 32 + 16 + dcol] = f2fp8(acc[ti][3][rg]);
            }
            float ps0 = acc[ti][0][rg] * asv0 + acc[ti][1][rg] * asv1;
            float pd0 = acc[ti][0][rg] * adv0 + acc[ti][1][rg] * adv1;
            float ps1 = acc[ti][2][rg] * asv0 + acc[ti][3][rg] * asv1;
            float pd1 = acc[ti][2][rg] * adv0 + acc[ti][3][rg] * adv1;
#pragma unroll
            for (int m = 1; m < 16; m <<= 1) {
                ps0 += __shfl_xor(ps0, m, 64);
                pd0 += __shfl_xor(pd0, m, 64);
                ps1 += __shfl_xor(ps1, m, 64);
                pd1 += __shfl_xor(pd1, m, 64);
            }
            if (dcol == 0) {
                if (row0 < N_NODES) {
                    ALS[(size_t)row0 * HEADS + tn] = ps0;
                    ALD[(size_t)row0 * HEADS + tn] = pd0;
                }
                if (row1 < N_NODES) {
                    ALS[(size_t)row1 * HEADS + tn] = ps1;
                    ALD[(size_t)row1 * HEADS + tn] = pd1;
                }
            }
        }
    }
}

// ---------------- wave MFMA GEMM (layer 3, N=32, fp8 A) ----------------

__global__ __launch_bounds__(256) void gemm_mfma_kernel(
    const unsigned char* __restrict__ A, const unsigned short* __restrict__ Bt,
    unsigned char* __restrict__ C,
    const float* __restrict__ a_src, const float* __restrict__ a_dst,
    float* __restrict__ ALS, float* __restrict__ ALD,
    int N, int K, int heads, int ntiles) {
    int wid = (blockIdx.x * blockDim.x + threadIdx.x) >> 6;
    if (wid >= ntiles) return;
    int ntN = N >> 5;
    int tm = wid / ntN, tn = wid - tm * ntN;
    int lane = threadIdx.x & 63;
    int r = lane & 15;
    int ko = (lane >> 4) * 8;
    f32x4 acc00 = {0.f,0.f,0.f,0.f}, acc01 = acc00, acc10 = acc00, acc11 = acc00;
    const unsigned char* Ar0 = A + (size_t)(tm * 32 + r) * K + ko;
    const unsigned char* Ar1 = A + (size_t)(tm * 32 + 16 + r) * K + ko;
    const unsigned short* Br0 = Bt + (size_t)(tn * 32 + r) * K + ko;
    const unsigned short* Br1 = Bt + (size_t)(tn * 32 + 16 + r) * K + ko;
    for (int k0 = 0; k0 < K; k0 += 32) {
        bf16x8 a0 = fp8x8_to_bf16(*(const uint2*)(Ar0 + k0));
        bf16x8 a1 = fp8x8_to_bf16(*(const uint2*)(Ar1 + k0));
        bf16x8 b0 = *(const bf16x8*)(Br0 + k0);
        bf16x8 b1 = *(const bf16x8*)(Br1 + k0);
        acc00 = __builtin_amdgcn_mfma_f32_16x16x32_bf16(a0, b0, acc00, 0, 0, 0);
        acc01 = __builtin_amdgcn_mfma_f32_16x16x32_bf16(a0, b1, acc01, 0, 0, 0);
        acc10 = __builtin_amdgcn_mfma_f32_16x16x32_bf16(a1, b0, acc10, 0, 0, 0);
        acc11 = __builtin_amdgcn_mfma_f32_16x16x32_bf16(a1, b1, acc11, 0, 0, 0);
    }
    int dcol = lane & 15;
    int drow = (lane >> 4) * 4;
    float asv0 = a_src[tn * 32 + dcol];
    float asv1 = a_src[tn * 32 + 16 + dcol];
    float adv0 = a_dst[tn * 32 + dcol];
    float adv1 = a_dst[tn * 32 + 16 + dcol];
#pragma unroll
    for (int rg = 0; rg < 4; ++rg) {
        int row0 = tm * 32 + drow + rg;
        int row1 = row0 + 16;
        C[(size_t)row0 * N + tn * 32 + dcol]      = f2fp8(acc00[rg]);
        C[(size_t)row0 * N + tn * 32 + 16 + dcol] = f2fp8(acc01[rg]);
        C[(size_t)row1 * N + tn * 32 + dcol]      = f2fp8(acc10[rg]);
        C[(size_t)row1 * N + tn * 32 + 16 + dcol] = f2fp8(acc11[rg]);
        float ps0 = acc00[rg] * asv0 + acc01[rg] * asv1;
        float pd0 = acc00[rg] * adv0 + acc01[rg] * adv1;
        float ps1 = acc10[rg] * asv0 + acc11[rg] * asv1;
        float pd1 = acc10[rg] * adv0 + acc11[rg] * adv1;
#pragma unroll
        for (int m = 1; m < 16; m <<= 1) {
            ps0 += __shfl_xor(ps0, m, 64);
            pd0 += __shfl_xor(pd0, m, 64);
            ps1 += __shfl_xor(ps1, m, 64);
            pd1 += __shfl_xor(pd1, m, 64);
        }
        if (dcol == 0) {
            ALS[(size_t)row0 * heads + tn] = ps0;
            ALD[(size_t)row0 * heads + tn] = pd0;
            ALS[(size_t)row1 * heads + tn] = ps1;
            ALD[(size_t)row1 * heads + tn] = pd1;
        }
    }
}

// ---------------- aggregation (quarter-split wave: 16 lanes/edge, 16B/lane) ----------------
// Quarter q (16 lanes) owns edge p+4q+j in a 16-edges-per-iteration masked loop:
// one wave-level scalar op (exp/leaky/load) covers 4 edges. Merge via shfl_xor 16, 32.

__global__ __launch_bounds__(256) void agg12_kernel(
    const unsigned char* __restrict__ Hb,
    const float* __restrict__ ALS, const float* __restrict__ ALD,
    const int* __restrict__ rowptr, const unsigned* __restrict__ srcoff,
    const float* __restrict__ bias, unsigned char* __restrict__ outb) {
    int wave = (blockIdx.x * blockDim.x + threadIdx.x) >> 6;
    int lane = threadIdx.x & 63;
    if (wave >= N_NODES) return;
    const int dst = wave;
    const int quarter = lane >> 4, hl = lane & 15;
    const int head = hl >> 1;               // 16 dims/lane -> head = hl*16/32
    const unsigned hb_lane = (unsigned)hl * 16;
    const int beg = rowptr[dst], end = rowptr[dst + 1];
    const float ald_h = ALD[dst * HEADS + head];
    float z = 0.f;
    f32x2 acc0 = {0.f, 0.f}, acc1 = acc0, acc2 = acc0, acc3 = acc0;
    f32x2 acc4 = acc0, acc5 = acc0, acc6 = acc0, acc7 = acc0;
    const int pq = beg + quarter * 4;
    for (int p = 0; p + beg < end; p += 16) {
        int i0 = pq + p, i1 = i0 + 1, i2 = i0 + 2, i3 = i0 + 3;
        bool a0v = i0 < end, a1v = i1 < end, a2v = i2 < end, a3v = i3 < end;
        unsigned o0 = srcoff[a0v ? i0 : beg];
        unsigned o1 = srcoff[a1v ? i1 : beg];
        unsigned o2 = srcoff[a2v ? i2 : beg];
        unsigned o3 = srcoff[a3v ? i3 : beg];
        float e0 = ALS[(o0 >> 5) + head] + ald_h;
        float e1 = ALS[(o1 >> 5) + head] + ald_h;
        float e2 = ALS[(o2 >> 5) + head] + ald_h;
        float e3 = ALS[(o3 >> 5) + head] + ald_h;
        uint4 w0 = *(const uint4*)(Hb + o0 + hb_lane);
        uint4 w1 = *(const uint4*)(Hb + o1 + hb_lane);
        uint4 w2 = *(const uint4*)(Hb + o2 + hb_lane);
        uint4 w3 = *(const uint4*)(Hb + o3 + hb_lane);
        e0 = fmaxf(e0, NEG_SLOPE * e0);
        e1 = fmaxf(e1, NEG_SLOPE * e1);
        e2 = fmaxf(e2, NEG_SLOPE * e2);
        e3 = fmaxf(e3, NEG_SLOPE * e3);
        float x0 = a0v ? __expf(e0) : 0.f;
        float x1 = a1v ? __expf(e1) : 0.f;
        float x2 = a2v ? __expf(e2) : 0.f;
        float x3 = a3v ? __expf(e3) : 0.f;
        z += (x0 + x1) + (x2 + x3);
        f32x2 v0 = {x0, x0}, v1 = {x1, x1}, v2 = {x2, x2}, v3 = {x3, x3};
        acc0 += v0 * fp8pair<false>(w0.x); acc1 += v0 * fp8pair<true>(w0.x);
        acc2 += v0 * fp8pair<false>(w0.y); acc3 += v0 * fp8pair<true>(w0.y);
        acc4 += v0 * fp8pair<false>(w0.z); acc5 += v0 * fp8pair<true>(w0.z);
        acc6 += v0 * fp8pair<false>(w0.w); acc7 += v0 * fp8pair<true>(w0.w);
        acc0 += v1 * fp8pair<false>(w1.x); acc1 += v1 * fp8pair<true>(w1.x);
        acc2 += v1 * fp8pair<false>(w1.y); acc3 += v1 * fp8pair<true>(w1.y);
        acc4 += v1 * fp8pair<false>(w1.z); acc5 += v1 * fp8pair<true>(w1.z);
        acc6 += v1 * fp8pair<false>(w1.w); acc7 += v1 * fp8pair<true>(w1.w);
        acc0 += v2 * fp8pair<false>(w2.x); acc1 += v2 * fp8pair<true>(w2.x);
        acc2 += v2 * fp8pair<false>(w2.y); acc3 += v2 * fp8pair<true>(w2.y);
        acc4 += v2 * fp8pair<false>(w2.z); acc5 += v2 * fp8pair<true>(w2.z);
        acc6 += v2 * fp8pair<false>(w2.w); acc7 += v2 * fp8pair<true>(w2.w);
        acc0 += v3 * fp8pair<false>(w3.x); acc1 += v3 * fp8pair<true>(w3.x);
        acc2 += v3 * fp8pair<false>(w3.y); acc3 += v3 * fp8pair<true>(w3.y);
        acc4 += v3 * fp8pair<false>(w3.z); acc5 += v3 * fp8pair<true>(w3.z);
        acc6 += v3 * fp8pair<false>(w3.w); acc7 += v3 * fp8pair<true>(w3.w);
    }
    // merge quarters: xor 16, then xor 32
#pragma unroll
    for (int m = 16; m <= 32; m <<= 1) {
        z += __shfl_xor(z, m, 64);
        acc0[0] += __shfl_xor(acc0[0], m, 64); acc0[1] += __shfl_xor(acc0[1], m, 64);
        acc1[0] += __shfl_xor(acc1[0], m, 64); acc1[1] += __shfl_xor(acc1[1], m, 64);
        acc2[0] += __shfl_xor(acc2[0], m, 64); acc2[1] += __shfl_xor(acc2[1], m, 64);
        acc3[0] += __shfl_xor(acc3[0], m, 64); acc3[1] += __shfl_xor(acc3[1], m, 64);
        acc4[0] += __shfl_xor(acc4[0], m, 64); acc4[1] += __shfl_xor(acc4[1], m, 64);
        acc5[0] += __shfl_xor(acc5[0], m, 64); acc5[1] += __shfl_xor(acc5[1], m, 64);
        acc6[0] += __shfl_xor(acc6[0], m, 64); acc6[1] += __shfl_xor(acc6[1], m, 64);
        acc7[0] += __shfl_xor(acc7[0], m, 64); acc7[1] += __shfl_xor(acc7[1], m, 64);
    }
    if (quarter == 0) {
        float inv = 1.f / z;
        float o[16] = {acc0[0], acc0[1], acc1[0], acc1[1],
                       acc2[0], acc2[1], acc3[0], acc3[1],
                       acc4[0], acc4[1], acc5[0], acc5[1],
                       acc6[0], acc6[1], acc7[0], acc7[1]};
        const float* bv = bias + hl * 16;
        unsigned r[4] = {0, 0, 0, 0};
#pragma unroll
        for (int j = 0; j < 16; ++j) {
            float v = o[j] * inv + bv[j];
            v = v > 0.f ? v : (expf(v) - 1.f);   // ELU
            r[j >> 2] |= ((unsigned)f2fp8(v)) << (8 * (j & 3));
        }
        *(uint4*)(outb + (size_t)dst * CDIM + hl * 16) = make_uint4(r[0], r[1], r[2], r[3]);
    }
}

// layer 3: 4-deep half-split structure; payload L2-resident.
__global__ __launch_bounds__(256) void agg3_kernel(
    const unsigned char* __restrict__ H3b,
    const float* __restrict__ ALS, const float* __restrict__ ALD,
    const int* __restrict__ rowptr, const unsigned* __restrict__ srcoff,
    const float* __restrict__ b3, float* __restrict__ out) {
    int wave = (blockIdx.x * blockDim.x + threadIdx.x) >> 6;
    int lane = threadIdx.x & 63;
    if (wave >= N_NODES) return;
    const int dst = wave;
    const int dim = lane & 31, half = lane >> 5;
    const int beg = rowptr[dst], end = rowptr[dst + 1];
    const float aldv = ALD[dst];
    float z = 0.f, acc = 0.f;
    int p = beg;
    for (; p + 8 <= end; p += 8) {
        const unsigned* sp = srcoff + p + half * 4;
        unsigned o0 = sp[0], o1 = sp[1], o2 = sp[2], o3 = sp[3];
        float e0 = ALS[o0 >> 8] + aldv;
        float e1 = ALS[o1 >> 8] + aldv;
        float e2 = ALS[o2 >> 8] + aldv;
        float e3 = ALS[o3 >> 8] + aldv;
        float h0 = fp8one(H3b[(o0 >> 3) + dim]);
        float h1 = fp8one(H3b[(o1 >> 3) + dim]);
        float h2 = fp8one(H3b[(o2 >> 3) + dim]);
        float h3 = fp8one(H3b[(o3 >> 3) + dim]);
        e0 = fmaxf(e0, NEG_SLOPE * e0);
        e1 = fmaxf(e1, NEG_SLOPE * e1);
        e2 = fmaxf(e2, NEG_SLOPE * e2);
        e3 = fmaxf(e3, NEG_SLOPE * e3);
        float x0 = __expf(e0), x1 = __expf(e1), x2 = __expf(e2), x3 = __expf(e3);
        z += (x0 + x1) + (x2 + x3);
        acc += x0 * h0 + x1 * h1 + x2 * h2 + x3 * h3;
    }
    for (; p < end; p += 2) {           // masked tail
        int idx = p + half;
        bool act = idx < end;
        unsigned o = srcoff[act ? idx : beg];
        float e = ALS[o >> 8] + aldv;
        e = fmaxf(e, NEG_SLOPE * e);
        float ex = act ? __expf(e) : 0.f;
        z += ex;
        acc += ex * fp8one(H3b[(o >> 3) + dim]);
    }
    z += __shfl_xor(z, 32, 64);
    acc += __shfl_xor(acc, 32, 64);
    if (half == 0) out[(size_t)dst * HID + dim] = acc / z + b3[dim];
}

// ---------------- pooling + classifier ----------------

__device__ inline int lower_bound_dev(const int* arr, int n, int key) {
    int lo = 0, hi = n;
    while (lo < hi) {
        int mid = (lo + hi) >> 1;
        if (arr[mid] < key) lo = mid + 1; else hi = mid;
    }
    return lo;
}

__global__ void pool_kernel(const float* __restrict__ act3, const int* __restrict__ batch,
                            float* __restrict__ pooled) {
    int g = blockIdx.x;
    __shared__ int slo, shi;
    if (threadIdx.x == 0) {
        slo = lower_bound_dev(batch, N_NODES, g);
        shi = lower_bound_dev(batch, N_NODES, g + 1);
    }
    __syncthreads();
    int lo = slo, hi = shi;
    int dim = threadIdx.x & 31;
    int grp = threadIdx.x >> 5; // 8 groups
    float s = 0.f;
    for (int i = lo + grp; i < hi; i += 8) s += act3[(size_t)i * HID + dim];
    __shared__ float red[8][HID + 1];
    red[grp][dim] = s;
    __syncthreads();
    if (grp == 0) {
        float t = 0.f;
#pragma unroll
        for (int j = 0; j < 8; ++j) t += red[j][dim];
        float cnt = (float)(hi - lo);
        pooled[g * HID + dim] = t / fmaxf(cnt, 1.f);
    }
}

__global__ void classify_kernel(const float* __restrict__ pooled, const float* __restrict__ Wc,
                                const float* __restrict__ bc, float* __restrict__ out) {
    int g = blockIdx.x;
    int lane = threadIdx.x;
    __shared__ float lg[CLASSES];
    __shared__ float lse;
    float logit = 0.f;
    if (lane < CLASSES) {
        logit = bc[lane];
        for (int k = 0; k < HID; ++k) logit += pooled[g * HID + k] * Wc[k * CLASSES + lane];
        lg[lane] = logit;
    }
    __syncthreads();
    if (lane == 0) {
        float m = lg[0];
        for (int i = 1; i < CLASSES; ++i) m = fmaxf(m, lg[i]);
        float s = 0.f;
        for (int i = 0; i < CLASSES; ++i) s += expf(lg[i] - m);
        lse = m + logf(s);
    }
    __syncthreads();
    if (lane < CLASSES) out[g * CLASSES + lane] = logit - lse;
}

// ---------------- launch ----------------

extern "C" void kernel_launch(void* const* d_in, const int* in_sizes, int n_in,
                              void* d_out, int out_size, void* d_ws, size_t ws_size,
                              hipStream_t stream) {
    const float* x   = (const float*)d_in[0];
    const int* ei    = (const int*)d_in[1];
    const int* batch = (const int*)d_in[2];
    const float* W1  = (const float*)d_in[3];
    const float* as1 = (const float*)d_in[4];
    const float* ad1 = (const float*)d_in[5];
    const float* b1  = (const float*)d_in[6];
    const float* W2  = (const float*)d_in[7];
    const float* as2 = (const float*)d_in[8];
    const float* ad2 = (const float*)d_in[9];
    const float* b2  = (const float*)d_in[10];
    const float* W3  = (const float*)d_in[11];
    const float* as3 = (const float*)d_in[12];
    const float* ad3 = (const float*)d_in[13];
    const float* b3  = (const float*)d_in[14];
    const float* Wc  = (const float*)d_in[15];
    const float* bc  = (const float*)d_in[16];
    float* out = (float*)d_out;

    char* ws = (char*)d_ws;
    size_t off = 0;
    auto walloc = [&](size_t bytes) -> void* {
        void* p = ws + off;
        off += (bytes + 255) & ~(size_t)255;
        return p;
    };
    unsigned char* Hb    = (unsigned char*)walloc((size_t)N_NODES * CDIM);  // fp8 messages
    unsigned char* ACTb  = (unsigned char*)walloc((size_t)N_NODES * CDIM);  // fp8 activations
    unsigned char* H3b   = (unsigned char*)walloc((size_t)N_NODES * HID);   // fp8
    float* ACT3   = (float*)walloc((size_t)N_NODES * HID * 4);
    float* ALS    = (float*)walloc((size_t)N_NODES * HEADS * 4);
    float* ALD    = (float*)walloc((size_t)N_NODES * HEADS * 4);
    unsigned short* W1t = (unsigned short*)walloc((size_t)CDIM * IN_F * 2);
    unsigned short* W2t = (unsigned short*)walloc((size_t)CDIM * CDIM * 2);
    unsigned short* W3t = (unsigned short*)walloc((size_t)HID * CDIM * 2);
    int* rowptr   = (int*)walloc((size_t)(N_NODES + 1) * 4);
    unsigned* srcoff = (unsigned*)walloc((size_t)ETOT * 4);
    int* bcursor  = (int*)walloc((size_t)NBUCK * 16 * 4);  // line-padded cursors
    int* bbase    = (int*)walloc((size_t)(NBUCK + 1) * 4);
    unsigned* staged = (unsigned*)walloc((size_t)NBUCK * BCAP * 4); // 8.1 MB
    float* pooled = (float*)walloc(GRAPHS * HID * 4);

    // CSR build: block-counted binning
    (void)hipMemsetAsync(bcursor, 0, (size_t)NBUCK * 16 * 4, stream);
    bin_kernel<<<BIN_BLOCKS, 256, 0, stream>>>(ei, bcursor, staged);
    bscan_kernel<<<1, 1024, 0, stream>>>(bcursor, bbase, rowptr);
    build_kernel<<<NBUCK, 256, 0, stream>>>(staged, bcursor, bbase, rowptr, srcoff);

    // weight transposes/casts
    trcast_kernel<<<ceil_div(CDIM * IN_F, 256), 256, 0, stream>>>(W1, W1t, IN_F, CDIM);
    trcast_kernel<<<ceil_div(CDIM * CDIM, 256), 256, 0, stream>>>(W2, W2t, CDIM, CDIM);
    trcast_kernel<<<ceil_div(HID * CDIM, 256), 256, 0, stream>>>(W3, W3t, CDIM, HID);

    const int gemm_blocks = ceil_div(N_NODES, 64); // 1563
    const int ntiles3  = (N_NODES / 32);           // 3125
    int agg_grid = ceil_div(N_NODES * 64, 256);

    // layer 1 (block gemm, f32 A with fused cast, fp8 C + fused al)
    gemm_block_kernel<IN_F, 0><<<gemm_blocks, 512, 0, stream>>>(
        x, W1t, Hb, as1, ad1, ALS, ALD);
    agg12_kernel<<<agg_grid, 256, 0, stream>>>(Hb, ALS, ALD, rowptr, srcoff, b1, ACTb);
    // layer 2 (fp8 A decoded to bf16 in staging)
    gemm_block_kernel<CDIM, 2><<<gemm_blocks, 512, 0, stream>>>(
        ACTb, W2t, Hb, as2, ad2, ALS, ALD);
    agg12_kernel<<<agg_grid, 256, 0, stream>>>(Hb, ALS, ALD, rowptr, srcoff, b2, ACTb);
    // layer 3 (1 head, 32 dims; fp8 A decoded in-register)
    gemm_mfma_kernel<<<ceil_div(ntiles3, 4), 256, 0, stream>>>(
        ACTb, W3t, H3b, as3, ad3, ALS, ALD, HID, CDIM, 1, ntiles3);
    agg3_kernel<<<agg_grid, 256, 0, stream>>>(H3b, ALS, ALD, rowptr, srcoff, b3, ACT3);
    // pool + classify
    pool_kernel<<<GRAPHS, 256, 0, stream>>>(ACT3, batch, pooled);
    classify_kernel<<<GRAPHS, 64, 0, stream>>>(pooled, Wc, bc, out);
}

// Round 15
// 492.510 us; speedup vs baseline: 1.1499x; 1.1499x over previous
//
#include <hip/hip_runtime.h>
#include <hip/hip_fp8.h>

#define N_NODES 100000
#define N_EDGES 1600000
#define ETOT (N_EDGES + N_NODES)
#define IN_F 128
#define HID 32
#define HEADS 8
#define CDIM (HEADS * HID) /* 256 */
#define GRAPHS 64
#define CLASSES 10
#define NEG_SLOPE 0.2f

#define BSHIFT 7                       /* 128 nodes per bucket */
#define NBUCK ((N_NODES + 127) >> BSHIFT) /* 782 */
#define BCAP 2600                      /* mean 2176, sigma ~45 -> 9+ sigma margin */
#define BIN_BLOCKS 160

static inline int ceil_div(int a, int b) { return (a + b - 1) / b; }

typedef __attribute__((ext_vector_type(8))) short bf16x8;
typedef __attribute__((ext_vector_type(4))) float f32x4;
typedef __attribute__((ext_vector_type(2))) float f32x2;

// bf16 <-> f32 helpers (round-to-nearest-even; inputs are finite)
__device__ inline unsigned short f2bf(float f) {
    unsigned u = __float_as_uint(f);
    unsigned r = (u + 0x7FFFu + ((u >> 16) & 1u)) >> 16;
    return (unsigned short)r;
}
__device__ inline float bf2f(unsigned short v) {
    return __uint_as_float(((unsigned)v) << 16);
}
// fp8 e4m3 (OCP) encode — HIP class (epilogues only, not hot loops)
__device__ inline unsigned char f2fp8(float f) {
    __hip_fp8_e4m3 v(f);
    return (unsigned char)v.__x;
}
// fp8 decode: HW packed cvt (byte-select is a compile-time template constant)
#if __has_builtin(__builtin_amdgcn_cvt_pk_f32_fp8)
template<bool HI>
__device__ inline f32x2 fp8pair(unsigned w) {
    return __builtin_amdgcn_cvt_pk_f32_fp8((int)w, HI);
}
#else
template<bool HI>
__device__ inline f32x2 fp8pair(unsigned w) {
    unsigned b0 = HI ? ((w >> 16) & 0xff) : (w & 0xff);
    unsigned b1 = HI ? (w >> 24) : ((w >> 8) & 0xff);
    __hip_fp8_e4m3 v0, v1;
    v0.__x = (__hip_fp8_storage_t)b0;
    v1.__x = (__hip_fp8_storage_t)b1;
    f32x2 r; r[0] = (float)v0; r[1] = (float)v1;
    return r;
}
#endif
__device__ inline float fp8one(unsigned char b) {
#if __has_builtin(__builtin_amdgcn_cvt_f32_fp8)
    return __builtin_amdgcn_cvt_f32_fp8((int)b, 0);
#else
    __hip_fp8_e4m3 v;
    v.__x = (__hip_fp8_storage_t)b;
    return (float)v;
#endif
}
// 8 fp8 (uint2) -> 8 bf16, ascending element order
__device__ inline bf16x8 fp8x8_to_bf16(uint2 w) {
    f32x2 p0 = fp8pair<false>(w.x), p1 = fp8pair<true>(w.x);
    f32x2 p2 = fp8pair<false>(w.y), p3 = fp8pair<true>(w.y);
    bf16x8 r;
    r[0] = (short)f2bf(p0[0]); r[1] = (short)f2bf(p0[1]);
    r[2] = (short)f2bf(p1[0]); r[3] = (short)f2bf(p1[1]);
    r[4] = (short)f2bf(p2[0]); r[5] = (short)f2bf(p2[1]);
    r[6] = (short)f2bf(p3[0]); r[7] = (short)f2bf(p3[1]);
    return r;
}

// ---------------- CSR build: block-counted binning (dense line writes) ----------------

__global__ __launch_bounds__(256) void bin_kernel(const int* __restrict__ ei,
                                                  int* __restrict__ bcursor,
                                                  unsigned* __restrict__ staged) {
    __shared__ int lhist[NBUCK];
    __shared__ int lbase[NBUCK];
    const int t = threadIdx.x;
    const int chunk = (ETOT + gridDim.x - 1) / gridDim.x;
    const int e0 = blockIdx.x * chunk;
    const int e1 = min(e0 + chunk, ETOT);
    for (int b = t; b < NBUCK; b += 256) lhist[b] = 0;
    __syncthreads();
    for (int e = e0 + t; e < e1; e += 256) {
        int d = (e < N_EDGES) ? ei[N_EDGES + e] : (e - N_EDGES);
        atomicAdd(&lhist[d >> BSHIFT], 1);
    }
    __syncthreads();
    for (int b = t; b < NBUCK; b += 256) {
        int c = lhist[b];
        lbase[b] = c ? atomicAdd(&bcursor[b * 16], c) : 0;
        lhist[b] = 0;
    }
    __syncthreads();
    for (int e = e0 + t; e < e1; e += 256) {
        int s, d;
        if (e < N_EDGES) { s = ei[e]; d = ei[N_EDGES + e]; }
        else { s = e - N_EDGES; d = s; }
        int b = d >> BSHIFT;
        int off = atomicAdd(&lhist[b], 1);
        staged[(size_t)b * BCAP + lbase[b] + off] =
            ((unsigned)s << BSHIFT) | (unsigned)(d & 127);
    }
}

__global__ __launch_bounds__(1024) void bscan_kernel(const int* __restrict__ bcursor,
                                                     int* __restrict__ bbase,
                                                     int* __restrict__ rowptr) {
    __shared__ int tmp[1024];
    int i = threadIdx.x;
    int v = (i < NBUCK) ? bcursor[i * 16] : 0;
    tmp[i] = v;
    __syncthreads();
    for (int off = 1; off < 1024; off <<= 1) {
        int t = (i >= off) ? tmp[i - off] : 0;
        __syncthreads();
        tmp[i] += t;
        __syncthreads();
    }
    if (i < NBUCK) bbase[i] = tmp[i] - v; // exclusive
    if (i == NBUCK - 1) { bbase[NBUCK] = tmp[i]; rowptr[N_NODES] = tmp[i]; }
}

// srcoff stores s*CDIM (byte offset into the fp8 payload row) — 32-bit.
__global__ __launch_bounds__(256) void build_kernel(
    const unsigned* __restrict__ staged, const int* __restrict__ bcursor,
    const int* __restrict__ bbase, int* __restrict__ rowptr, unsigned* __restrict__ srcoff) {
    int b = blockIdx.x;
    int cnt = bcursor[b * 16];
    int base = bbase[b];
    __shared__ int lcnt[128];
    __shared__ int lscan[128];
    int t = threadIdx.x;
    if (t < 128) lcnt[t] = 0;
    __syncthreads();
    const unsigned* st = staged + (size_t)b * BCAP;
    for (int i = t; i < cnt; i += 256) atomicAdd(&lcnt[st[i] & 127], 1);
    __syncthreads();
    if (t < 128) lscan[t] = lcnt[t];
    __syncthreads();
    for (int off = 1; off < 128; off <<= 1) {
        int v = 0;
        if (t < 128 && t >= off) v = lscan[t - off];
        __syncthreads();
        if (t < 128) lscan[t] += v;
        __syncthreads();
    }
    int node0 = b << BSHIFT;
    if (t < 128 && node0 + t < N_NODES)
        rowptr[node0 + t] = base + (t == 0 ? 0 : lscan[t - 1]);
    __syncthreads();
    if (t < 128) lcnt[t] = (t == 0 ? 0 : lscan[t - 1]);
    __syncthreads();
    for (int i = t; i < cnt; i += 256) {
        unsigned v = st[i];
        int pos = base + atomicAdd(&lcnt[v & 127], 1);
        srcoff[pos] = (v >> BSHIFT) << 8;   // s * CDIM
    }
}

// ---------------- casts ----------------

// Wt[n][k] = bf16(W[k][n]);  W is [K,N]
__global__ void trcast_kernel(const float* __restrict__ W,
                              unsigned short* __restrict__ Wt, int K, int N) {
    int i = blockIdx.x * blockDim.x + threadIdx.x;
    if (i >= N * K) return;
    int n = i / K, k = i % K;
    Wt[i] = f2bf(W[(size_t)k * N + n]);
}

// ---------------- Block MFMA GEMM (layers 1/2): C[M,256] fp8 = A[M,K] @ Bt[256,K] ----------------
// AMODE: 0 = f32 A (casts to bf16 in staging), 2 = fp8 A (HW-decodes to bf16 in staging).

template<int K, int AMODE>
__global__ __launch_bounds__(512) void gemm_block_kernel(
    const void* __restrict__ Aptr, const unsigned short* __restrict__ Bt,
    unsigned char* __restrict__ C,
    const float* __restrict__ a_src, const float* __restrict__ a_dst,
    float* __restrict__ ALS, float* __restrict__ ALD) {
    constexpr int LDK = K + 8;
    __shared__ unsigned short Alds[64 * LDK];
    const int t = threadIdx.x;
    const int brow = blockIdx.x * 64;

    if (AMODE == 0) {
        const float* A = (const float*)Aptr;
        constexpr int CG = K / 4;
#pragma unroll
        for (int i = 0; i < 64 * CG / 512; ++i) {
            int slot = t + i * 512;
            int row = slot / CG, cg = slot % CG;
            int grow = brow + row;
            float4 v = make_float4(0.f, 0.f, 0.f, 0.f);
            if (grow < N_NODES) v = *(const float4*)(A + (size_t)grow * K + cg * 4);
            ushort4 o;
            o.x = f2bf(v.x); o.y = f2bf(v.y); o.z = f2bf(v.z); o.w = f2bf(v.w);
            *(ushort4*)(Alds + row * LDK + cg * 4) = o;
        }
    } else {
        const unsigned char* A = (const unsigned char*)Aptr;
        constexpr int CG = K / 8;           // 8 fp8 per slot
#pragma unroll
        for (int i = 0; i < 64 * CG / 512; ++i) {
            int slot = t + i * 512;
            int row = slot / CG, cg = slot % CG;
            int grow = brow + row;
            uint2 v = make_uint2(0u, 0u);
            if (grow < N_NODES) v = *(const uint2*)(A + (size_t)grow * K + cg * 8);
            *(bf16x8*)(Alds + row * LDK + cg * 8) = fp8x8_to_bf16(v);
        }
    }
    __syncthreads();

    const int wv = t >> 6;
    const int lane = t & 63;
    const int rhalf = wv & 1;
    const int cpair = wv >> 1;
    const int r = lane & 15;
    const int ko0 = (lane >> 4) * 8;
    const unsigned short* Ar0 = Alds + (rhalf * 32 + r) * LDK + ko0;
    const unsigned short* Ar1 = Alds + (rhalf * 32 + 16 + r) * LDK + ko0;
    const unsigned short* Bq = Bt + (size_t)(cpair * 64 + r) * K + ko0;
    f32x4 acc[2][4];
#pragma unroll
    for (int a = 0; a < 2; ++a)
#pragma unroll
        for (int b = 0; b < 4; ++b) acc[a][b] = {0.f, 0.f, 0.f, 0.f};
#pragma unroll
    for (int k0 = 0; k0 < K; k0 += 32) {
        bf16x8 a0 = *(const bf16x8*)(Ar0 + k0);
        bf16x8 a1 = *(const bf16x8*)(Ar1 + k0);
        bf16x8 b0 = *(const bf16x8*)(Bq + k0);
        bf16x8 b1 = *(const bf16x8*)(Bq + (size_t)16 * K + k0);
        bf16x8 b2 = *(const bf16x8*)(Bq + (size_t)32 * K + k0);
        bf16x8 b3 = *(const bf16x8*)(Bq + (size_t)48 * K + k0);
        acc[0][0] = __builtin_amdgcn_mfma_f32_16x16x32_bf16(a0, b0, acc[0][0], 0, 0, 0);
        acc[0][1] = __builtin_amdgcn_mfma_f32_16x16x32_bf16(a0, b1, acc[0][1], 0, 0, 0);
        acc[0][2] = __builtin_amdgcn_mfma_f32_16x16x32_bf16(a1, b0, acc[0][2], 0, 0, 0);
        acc[0][3] = __builtin_amdgcn_mfma_f32_16x16x32_bf16(a1, b1, acc[0][3], 0, 0, 0);
        acc[1][0] = __builtin_amdgcn_mfma_f32_16x16x32_bf16(a0, b2, acc[1][0], 0, 0, 0);
        acc[1][1] = __builtin_amdgcn_mfma_f32_16x16x32_bf16(a0, b3, acc[1][1], 0, 0, 0);
        acc[1][2] = __builtin_amdgcn_mfma_f32_16x16x32_bf16(a1, b2, acc[1][2], 0, 0, 0);
        acc[1][3] = __builtin_amdgcn_mfma_f32_16x16x32_bf16(a1, b3, acc[1][3], 0, 0, 0);
    }

    const int dcol = lane & 15;
    const int drow = (lane >> 4) * 4;
#pragma unroll
    for (int ti = 0; ti < 2; ++ti) {
        int tn = cpair * 2 + ti;
        float asv0 = a_src[tn * 32 + dcol];
        float asv1 = a_src[tn * 32 + 16 + dcol];
        float adv0 = a_dst[tn * 32 + dcol];
        float adv1 = a_dst[tn * 32 + 16 + dcol];
#pragma unroll
        for (int rg = 0; rg < 4; ++rg) {
            int row0 = brow + rhalf * 32 + drow + rg;
            int row1 = row0 + 16;
            if (row0 < N_NODES) {
                C[(size_t)row0 * CDIM + tn * 32 + dcol]      = f2fp8(acc[ti][0][rg]);
                C[(size_t)row0 * CDIM + tn * 32 + 16 + dcol] = f2fp8(acc[ti][1][rg]);
            }
            if (row1 < N_NODES) {
                C[(size_t)row1 * CDIM + tn * 32 + dcol]      = f2fp8(acc[ti][2][rg]);
                C[(size_t)row1 * CDIM + tn * 32 + 16 + dcol] = f2fp8(acc[ti][3][rg]);
            }
            float ps0 = acc[ti][0][rg] * asv0 + acc[ti][1][rg] * asv1;
            float pd0 = acc[ti][0][rg] * adv0 + acc[ti][1][rg] * adv1;
            float ps1 = acc[ti][2][rg] * asv0 + acc[ti][3][rg] * asv1;
            float pd1 = acc[ti][2][rg] * adv0 + acc[ti][3][rg] * adv1;
#pragma unroll
            for (int m = 1; m < 16; m <<= 1) {
                ps0 += __shfl_xor(ps0, m, 64);
                pd0 += __shfl_xor(pd0, m, 64);
                ps1 += __shfl_xor(ps1, m, 64);
                pd1 += __shfl_xor(pd1, m, 64);
            }
            if (dcol == 0) {
                if (row0 < N_NODES) {
                    ALS[(size_t)row0 * HEADS + tn] = ps0;
                    ALD[(size_t)row0 * HEADS + tn] = pd0;
                }
                if (row1 < N_NODES) {
                    ALS[(size_t)row1 * HEADS + tn] = ps1;
                    ALD[(size_t)row1 * HEADS + tn] = pd1;
                }
            }
        }
    }
}

// ---------------- wave MFMA GEMM (layer 3, N=32, fp8 A) ----------------

__global__ __launch_bounds__(256) void gemm_mfma_kernel(
    const unsigned char* __restrict__ A, const unsigned short* __restrict__ Bt,
    unsigned char* __restrict__ C,
    const float* __restrict__ a_src, const float* __restrict__ a_dst,
    float* __restrict__ ALS, float* __restrict__ ALD,
    int N, int K, int heads, int ntiles) {
    int wid = (blockIdx.x * blockDim.x + threadIdx.x) >> 6;
    if (wid >= ntiles) return;
    int ntN = N >> 5;
    int tm = wid / ntN, tn = wid - tm * ntN;
    int lane = threadIdx.x & 63;
    int r = lane & 15;
    int ko = (lane >> 4) * 8;
    f32x4 acc00 = {0.f,0.f,0.f,0.f}, acc01 = acc00, acc10 = acc00, acc11 = acc00;
    const unsigned char* Ar0 = A + (size_t)(tm * 32 + r) * K + ko;
    const unsigned char* Ar1 = A + (size_t)(tm * 32 + 16 + r) * K + ko;
    const unsigned short* Br0 = Bt + (size_t)(tn * 32 + r) * K + ko;
    const unsigned short* Br1 = Bt + (size_t)(tn * 32 + 16 + r) * K + ko;
    for (int k0 = 0; k0 < K; k0 += 32) {
        bf16x8 a0 = fp8x8_to_bf16(*(const uint2*)(Ar0 + k0));
        bf16x8 a1 = fp8x8_to_bf16(*(const uint2*)(Ar1 + k0));
        bf16x8 b0 = *(const bf16x8*)(Br0 + k0);
        bf16x8 b1 = *(const bf16x8*)(Br1 + k0);
        acc00 = __builtin_amdgcn_mfma_f32_16x16x32_bf16(a0, b0, acc00, 0, 0, 0);
        acc01 = __builtin_amdgcn_mfma_f32_16x16x32_bf16(a0, b1, acc01, 0, 0, 0);
        acc10 = __builtin_amdgcn_mfma_f32_16x16x32_bf16(a1, b0, acc10, 0, 0, 0);
        acc11 = __builtin_amdgcn_mfma_f32_16x16x32_bf16(a1, b1, acc11, 0, 0, 0);
    }
    int dcol = lane & 15;
    int drow = (lane >> 4) * 4;
    float asv0 = a_src[tn * 32 + dcol];
    float asv1 = a_src[tn * 32 + 16 + dcol];
    float adv0 = a_dst[tn * 32 + dcol];
    float adv1 = a_dst[tn * 32 + 16 + dcol];
#pragma unroll
    for (int rg = 0; rg < 4; ++rg) {
        int row0 = tm * 32 + drow + rg;
        int row1 = row0 + 16;
        C[(size_t)row0 * N + tn * 32 + dcol]      = f2fp8(acc00[rg]);
        C[(size_t)row0 * N + tn * 32 + 16 + dcol] = f2fp8(acc01[rg]);
        C[(size_t)row1 * N + tn * 32 + dcol]      = f2fp8(acc10[rg]);
        C[(size_t)row1 * N + tn * 32 + 16 + dcol] = f2fp8(acc11[rg]);
        float ps0 = acc00[rg] * asv0 + acc01[rg] * asv1;
        float pd0 = acc00[rg] * adv0 + acc01[rg] * adv1;
        float ps1 = acc10[rg] * asv0 + acc11[rg] * asv1;
        float pd1 = acc10[rg] * adv0 + acc11[rg] * adv1;
#pragma unroll
        for (int m = 1; m < 16; m <<= 1) {
            ps0 += __shfl_xor(ps0, m, 64);
            pd0 += __shfl_xor(pd0, m, 64);
            ps1 += __shfl_xor(ps1, m, 64);
            pd1 += __shfl_xor(pd1, m, 64);
        }
        if (dcol == 0) {
            ALS[(size_t)row0 * heads + tn] = ps0;
            ALD[(size_t)row0 * heads + tn] = pd0;
            ALS[(size_t)row1 * heads + tn] = ps1;
            ALD[(size_t)row1 * heads + tn] = pd1;
        }
    }
}

// ---------------- aggregation (half-split wave, 4 edges in flight per half) ----------------

__global__ __launch_bounds__(256) void agg12_kernel(
    const unsigned char* __restrict__ Hb,
    const float* __restrict__ ALS, const float* __restrict__ ALD,
    const int* __restrict__ rowptr, const unsigned* __restrict__ srcoff,
    const float* __restrict__ bias, unsigned char* __restrict__ outb) {
    int wave = (blockIdx.x * blockDim.x + threadIdx.x) >> 6;
    int lane = threadIdx.x & 63;
    if (wave >= N_NODES) return;
    const int dst = wave;
    const int half = lane >> 5, hl = lane & 31;
    const int head = hl >> 2;
    const unsigned hb_lane = (unsigned)hl * 8;
    const int beg = rowptr[dst], end = rowptr[dst + 1];
    const float ald_h = ALD[dst * HEADS + head];
    float z = 0.f;
    f32x2 acc0 = {0.f, 0.f}, acc1 = acc0, acc2 = acc0, acc3 = acc0;
    int p = beg;
    for (; p + 8 <= end; p += 8) {
        const unsigned* sp = srcoff + p + half * 4;
        unsigned o0 = sp[0], o1 = sp[1], o2 = sp[2], o3 = sp[3];
        float e0 = ALS[(o0 >> 5) + head] + ald_h;
        float e1 = ALS[(o1 >> 5) + head] + ald_h;
        float e2 = ALS[(o2 >> 5) + head] + ald_h;
        float e3 = ALS[(o3 >> 5) + head] + ald_h;
        uint2 w0 = *(const uint2*)(Hb + o0 + hb_lane);
        uint2 w1 = *(const uint2*)(Hb + o1 + hb_lane);
        uint2 w2 = *(const uint2*)(Hb + o2 + hb_lane);
        uint2 w3 = *(const uint2*)(Hb + o3 + hb_lane);
        e0 = fmaxf(e0, NEG_SLOPE * e0);
        e1 = fmaxf(e1, NEG_SLOPE * e1);
        e2 = fmaxf(e2, NEG_SLOPE * e2);
        e3 = fmaxf(e3, NEG_SLOPE * e3);
        float x0 = __expf(e0), x1 = __expf(e1), x2 = __expf(e2), x3 = __expf(e3);
        z += (x0 + x1) + (x2 + x3);
        f32x2 v0 = {x0, x0}, v1 = {x1, x1}, v2 = {x2, x2}, v3 = {x3, x3};
        acc0 += v0 * fp8pair<false>(w0.x);
        acc1 += v0 * fp8pair<true>(w0.x);
        acc2 += v0 * fp8pair<false>(w0.y);
        acc3 += v0 * fp8pair<true>(w0.y);
        acc0 += v1 * fp8pair<false>(w1.x);
        acc1 += v1 * fp8pair<true>(w1.x);
        acc2 += v1 * fp8pair<false>(w1.y);
        acc3 += v1 * fp8pair<true>(w1.y);
        acc0 += v2 * fp8pair<false>(w2.x);
        acc1 += v2 * fp8pair<true>(w2.x);
        acc2 += v2 * fp8pair<false>(w2.y);
        acc3 += v2 * fp8pair<true>(w2.y);
        acc0 += v3 * fp8pair<false>(w3.x);
        acc1 += v3 * fp8pair<true>(w3.x);
        acc2 += v3 * fp8pair<false>(w3.y);
        acc3 += v3 * fp8pair<true>(w3.y);
    }
    for (; p < end; p += 2) {           // masked tail: up to 7 edges remain
        int idx = p + half;
        bool act = idx < end;
        unsigned oa = srcoff[act ? idx : beg];
        float ea = ALS[(oa >> 5) + head] + ald_h;
        ea = fmaxf(ea, NEG_SLOPE * ea);
        float xa = act ? __expf(ea) : 0.f;
        uint2 wa = *(const uint2*)(Hb + oa + hb_lane);
        z += xa;
        f32x2 va = {xa, xa};
        acc0 += va * fp8pair<false>(wa.x);
        acc1 += va * fp8pair<true>(wa.x);
        acc2 += va * fp8pair<false>(wa.y);
        acc3 += va * fp8pair<true>(wa.y);
    }
    // merge the two halves
    z += __shfl_xor(z, 32, 64);
    acc0[0] += __shfl_xor(acc0[0], 32, 64); acc0[1] += __shfl_xor(acc0[1], 32, 64);
    acc1[0] += __shfl_xor(acc1[0], 32, 64); acc1[1] += __shfl_xor(acc1[1], 32, 64);
    acc2[0] += __shfl_xor(acc2[0], 32, 64); acc2[1] += __shfl_xor(acc2[1], 32, 64);
    acc3[0] += __shfl_xor(acc3[0], 32, 64); acc3[1] += __shfl_xor(acc3[1], 32, 64);
    if (half == 0) {
        float inv = 1.f / z;
        float o[8] = {acc0[0], acc0[1], acc1[0], acc1[1],
                      acc2[0], acc2[1], acc3[0], acc3[1]};
        const float* bv = bias + hl * 8;
        unsigned r0 = 0, r1 = 0;
#pragma unroll
        for (int j = 0; j < 8; ++j) {
            float v = o[j] * inv + bv[j];
            v = v > 0.f ? v : (expf(v) - 1.f);   // ELU
            unsigned b = (unsigned)f2fp8(v);
            if (j < 4) r0 |= b << (8 * j);
            else       r1 |= b << (8 * (j - 4));
        }
        *(uint2*)(outb + (size_t)dst * CDIM + hl * 8) = make_uint2(r0, r1);
    }
}

// layer 3: same 4-deep half-split structure; payload L2-resident.
__global__ __launch_bounds__(256) void agg3_kernel(
    const unsigned char* __restrict__ H3b,
    const float* __restrict__ ALS, const float* __restrict__ ALD,
    const int* __restrict__ rowptr, const unsigned* __restrict__ srcoff,
    const float* __restrict__ b3, float* __restrict__ out) {
    int wave = (blockIdx.x * blockDim.x + threadIdx.x) >> 6;
    int lane = threadIdx.x & 63;
    if (wave >= N_NODES) return;
    const int dst = wave;
    const int dim = lane & 31, half = lane >> 5;
    const int beg = rowptr[dst], end = rowptr[dst + 1];
    const float aldv = ALD[dst];
    float z = 0.f, acc = 0.f;
    int p = beg;
    for (; p + 8 <= end; p += 8) {
        const unsigned* sp = srcoff + p + half * 4;
        unsigned o0 = sp[0], o1 = sp[1], o2 = sp[2], o3 = sp[3];
        float e0 = ALS[o0 >> 8] + aldv;
        float e1 = ALS[o1 >> 8] + aldv;
        float e2 = ALS[o2 >> 8] + aldv;
        float e3 = ALS[o3 >> 8] + aldv;
        float h0 = fp8one(H3b[(o0 >> 3) + dim]);
        float h1 = fp8one(H3b[(o1 >> 3) + dim]);
        float h2 = fp8one(H3b[(o2 >> 3) + dim]);
        float h3 = fp8one(H3b[(o3 >> 3) + dim]);
        e0 = fmaxf(e0, NEG_SLOPE * e0);
        e1 = fmaxf(e1, NEG_SLOPE * e1);
        e2 = fmaxf(e2, NEG_SLOPE * e2);
        e3 = fmaxf(e3, NEG_SLOPE * e3);
        float x0 = __expf(e0), x1 = __expf(e1), x2 = __expf(e2), x3 = __expf(e3);
        z += (x0 + x1) + (x2 + x3);
        acc += x0 * h0 + x1 * h1 + x2 * h2 + x3 * h3;
    }
    for (; p < end; p += 2) {           // masked tail
        int idx = p + half;
        bool act = idx < end;
        unsigned o = srcoff[act ? idx : beg];
        float e = ALS[o >> 8] + aldv;
        e = fmaxf(e, NEG_SLOPE * e);
        float ex = act ? __expf(e) : 0.f;
        z += ex;
        acc += ex * fp8one(H3b[(o >> 3) + dim]);
    }
    z += __shfl_xor(z, 32, 64);
    acc += __shfl_xor(acc, 32, 64);
    if (half == 0) out[(size_t)dst * HID + dim] = acc / z + b3[dim];
}

// ---------------- pooling + classifier ----------------

__device__ inline int lower_bound_dev(const int* arr, int n, int key) {
    int lo = 0, hi = n;
    while (lo < hi) {
        int mid = (lo + hi) >> 1;
        if (arr[mid] < key) lo = mid + 1; else hi = mid;
    }
    return lo;
}

__global__ void pool_kernel(const float* __restrict__ act3, const int* __restrict__ batch,
                            float* __restrict__ pooled) {
    int g = blockIdx.x;
    __shared__ int slo, shi;
    if (threadIdx.x == 0) {
        slo = lower_bound_dev(batch, N_NODES, g);
        shi = lower_bound_dev(batch, N_NODES, g + 1);
    }
    __syncthreads();
    int lo = slo, hi = shi;
    int dim = threadIdx.x & 31;
    int grp = threadIdx.x >> 5; // 8 groups
    float s = 0.f;
    for (int i = lo + grp; i < hi; i += 8) s += act3[(size_t)i * HID + dim];
    __shared__ float red[8][HID + 1];
    red[grp][dim] = s;
    __syncthreads();
    if (grp == 0) {
        float t = 0.f;
#pragma unroll
        for (int j = 0; j < 8; ++j) t += red[j][dim];
        float cnt = (float)(hi - lo);
        pooled[g * HID + dim] = t / fmaxf(cnt, 1.f);
    }
}

__global__ void classify_kernel(const float* __restrict__ pooled, const float* __restrict__ Wc,
                                const float* __restrict__ bc, float* __restrict__ out) {
    int g = blockIdx.x;
    int lane = threadIdx.x;
    __shared__ float lg[CLASSES];
    __shared__ float lse;
    float logit = 0.f;
    if (lane < CLASSES) {
        logit = bc[lane];
        for (int k = 0; k < HID; ++k) logit += pooled[g * HID + k] * Wc[k * CLASSES + lane];
        lg[lane] = logit;
    }
    __syncthreads();
    if (lane == 0) {
        float m = lg[0];
        for (int i = 1; i < CLASSES; ++i) m = fmaxf(m, lg[i]);
        float s = 0.f;
        for (int i = 0; i < CLASSES; ++i) s += expf(lg[i] - m);
        lse = m + logf(s);
    }
    __syncthreads();
    if (lane < CLASSES) out[g * CLASSES + lane] = logit - lse;
}

// ---------------- launch ----------------

extern "C" void kernel_launch(void* const* d_in, const int* in_sizes, int n_in,
                              void* d_out, int out_size, void* d_ws, size_t ws_size,
                              hipStream_t stream) {
    const float* x   = (const float*)d_in[0];
    const int* ei    = (const int*)d_in[1];
    const int* batch = (const int*)d_in[2];
    const float* W1  = (const float*)d_in[3];
    const float* as1 = (const float*)d_in[4];
    const float* ad1 = (const float*)d_in[5];
    const float* b1  = (const float*)d_in[6];
    const float* W2  = (const float*)d_in[7];
    const float* as2 = (const float*)d_in[8];
    const float* ad2 = (const float*)d_in[9];
    const float* b2  = (const float*)d_in[10];
    const float* W3  = (const float*)d_in[11];
    const float* as3 = (const float*)d_in[12];
    const float* ad3 = (const float*)d_in[13];
    const float* b3  = (const float*)d_in[14];
    const float* Wc  = (const float*)d_in[15];
    const float* bc  = (const float*)d_in[16];
    float* out = (float*)d_out;

    char* ws = (char*)d_ws;
    size_t off = 0;
    auto walloc = [&](size_t bytes) -> void* {
        void* p = ws + off;
        off += (bytes + 255) & ~(size_t)255;
        return p;
    };
    unsigned char* Hb    = (unsigned char*)walloc((size_t)N_NODES * CDIM);  // fp8 messages
    unsigned char* ACTb  = (unsigned char*)walloc((size_t)N_NODES * CDIM);  // fp8 activations
    unsigned char* H3b   = (unsigned char*)walloc((size_t)N_NODES * HID);   // fp8
    float* ACT3   = (float*)walloc((size_t)N_NODES * HID * 4);
    float* ALS    = (float*)walloc((size_t)N_NODES * HEADS * 4);
    float* ALD    = (float*)walloc((size_t)N_NODES * HEADS * 4);
    unsigned short* W1t = (unsigned short*)walloc((size_t)CDIM * IN_F * 2);
    unsigned short* W2t = (unsigned short*)walloc((size_t)CDIM * CDIM * 2);
    unsigned short* W3t = (unsigned short*)walloc((size_t)HID * CDIM * 2);
    int* rowptr   = (int*)walloc((size_t)(N_NODES + 1) * 4);
    unsigned* srcoff = (unsigned*)walloc((size_t)ETOT * 4);
    int* bcursor  = (int*)walloc((size_t)NBUCK * 16 * 4);  // line-padded cursors
    int* bbase    = (int*)walloc((size_t)(NBUCK + 1) * 4);
    unsigned* staged = (unsigned*)walloc((size_t)NBUCK * BCAP * 4); // 8.1 MB
    float* pooled = (float*)walloc(GRAPHS * HID * 4);

    // CSR build: block-counted binning
    (void)hipMemsetAsync(bcursor, 0, (size_t)NBUCK * 16 * 4, stream);
    bin_kernel<<<BIN_BLOCKS, 256, 0, stream>>>(ei, bcursor, staged);
    bscan_kernel<<<1, 1024, 0, stream>>>(bcursor, bbase, rowptr);
    build_kernel<<<NBUCK, 256, 0, stream>>>(staged, bcursor, bbase, rowptr, srcoff);

    // weight transposes/casts
    trcast_kernel<<<ceil_div(CDIM * IN_F, 256), 256, 0, stream>>>(W1, W1t, IN_F, CDIM);
    trcast_kernel<<<ceil_div(CDIM * CDIM, 256), 256, 0, stream>>>(W2, W2t, CDIM, CDIM);
    trcast_kernel<<<ceil_div(HID * CDIM, 256), 256, 0, stream>>>(W3, W3t, CDIM, HID);

    const int gemm_blocks = ceil_div(N_NODES, 64); // 1563
    const int ntiles3  = (N_NODES / 32);           // 3125
    int agg_grid = ceil_div(N_NODES * 64, 256);

    // layer 1 (block gemm, f32 A with fused cast, fp8 C + fused al)
    gemm_block_kernel<IN_F, 0><<<gemm_blocks, 512, 0, stream>>>(
        x, W1t, Hb, as1, ad1, ALS, ALD);
    agg12_kernel<<<agg_grid, 256, 0, stream>>>(Hb, ALS, ALD, rowptr, srcoff, b1, ACTb);
    // layer 2 (fp8 A decoded to bf16 in staging)
    gemm_block_kernel<CDIM, 2><<<gemm_blocks, 512, 0, stream>>>(
        ACTb, W2t, Hb, as2, ad2, ALS, ALD);
    agg12_kernel<<<agg_grid, 256, 0, stream>>>(Hb, ALS, ALD, rowptr, srcoff, b2, ACTb);
    // layer 3 (1 head, 32 dims; fp8 A decoded in-register)
    gemm_mfma_kernel<<<ceil_div(ntiles3, 4), 256, 0, stream>>>(
        ACTb, W3t, H3b, as3, ad3, ALS, ALD, HID, CDIM, 1, ntiles3);
    agg3_kernel<<<agg_grid, 256, 0, stream>>>(H3b, ALS, ALD, rowptr, srcoff, b3, ACT3);
    // pool + classify
    pool_kernel<<<GRAPHS, 256, 0, stream>>>(ACT3, batch, pooled);
    classify_kernel<<<GRAPHS, 64, 0, stream>>>(pooled, Wc, bc, out);
}